// Round 1
// baseline (1538.399 us; speedup 1.0000x reference)
//
#include <hip/hip_runtime.h>
#include <math.h>

// Problem constants (B=2, N=2048, D=1024, H=16, K=V=64)
#define TK 16
#define TILE 64
#define LDSP 68   // padded LDS stride (68*4B = 272B, 16B-aligned, breaks pow2 banks)

// C[M][N] = A[M][K] * W[N][K]^T   (W row-major [N][K] — "B transposed" layout)
__global__ __launch_bounds__(256) void gemm_bt_kernel(
    const float* __restrict__ A, const float* __restrict__ W,
    float* __restrict__ C, int M, int N, int K)
{
    __shared__ alignas(16) float As[TK][LDSP];
    __shared__ alignas(16) float Bs[TK][LDSP];
    const int t  = threadIdx.x;
    const int tx = t & 15, ty = t >> 4;
    const int m0 = blockIdx.y * TILE;
    const int n0 = blockIdx.x * TILE;
    const int lrow = t >> 2;          // 0..63
    const int lc4  = (t & 3) << 2;    // 0,4,8,12
    float acc[4][4] = {};
    for (int k0 = 0; k0 < K; k0 += TK) {
        const float4 av = *(const float4*)&A[(size_t)(m0 + lrow) * K + k0 + lc4];
        const float4 wv = *(const float4*)&W[(size_t)(n0 + lrow) * K + k0 + lc4];
        As[lc4 + 0][lrow] = av.x; As[lc4 + 1][lrow] = av.y;
        As[lc4 + 2][lrow] = av.z; As[lc4 + 3][lrow] = av.w;
        Bs[lc4 + 0][lrow] = wv.x; Bs[lc4 + 1][lrow] = wv.y;
        Bs[lc4 + 2][lrow] = wv.z; Bs[lc4 + 3][lrow] = wv.w;
        __syncthreads();
        #pragma unroll
        for (int kk = 0; kk < TK; ++kk) {
            const float4 a4 = *(const float4*)&As[kk][ty * 4];
            const float4 b4 = *(const float4*)&Bs[kk][tx * 4];
            const float a[4] = {a4.x, a4.y, a4.z, a4.w};
            const float b[4] = {b4.x, b4.y, b4.z, b4.w};
            #pragma unroll
            for (int i = 0; i < 4; ++i)
                #pragma unroll
                for (int j = 0; j < 4; ++j)
                    acc[i][j] = fmaf(a[i], b[j], acc[i][j]);
        }
        __syncthreads();
    }
    #pragma unroll
    for (int i = 0; i < 4; ++i) {
        *(float4*)&C[(size_t)(m0 + ty * 4 + i) * N + n0 + tx * 4] =
            make_float4(acc[i][0], acc[i][1], acc[i][2], acc[i][3]);
    }
}

// C[M][N] = A[M][K] * W[K][N]   (W row-major [K][N] — normal layout, N multiple of 64)
__global__ __launch_bounds__(256) void gemm_bn_kernel(
    const float* __restrict__ A, const float* __restrict__ W,
    float* __restrict__ C, int M, int N, int K)
{
    __shared__ alignas(16) float As[TK][LDSP];
    __shared__ alignas(16) float Bs[TK][LDSP];
    const int t  = threadIdx.x;
    const int tx = t & 15, ty = t >> 4;
    const int m0 = blockIdx.y * TILE;
    const int n0 = blockIdx.x * TILE;
    const int lrow = t >> 2;          // 0..63
    const int lc4  = (t & 3) << 2;    // 0,4,8,12
    const int brow = t >> 4;          // 0..15 (k within tile)
    const int bc4  = (t & 15) << 2;   // 0..60 (n within tile)
    float acc[4][4] = {};
    for (int k0 = 0; k0 < K; k0 += TK) {
        const float4 av = *(const float4*)&A[(size_t)(m0 + lrow) * K + k0 + lc4];
        As[lc4 + 0][lrow] = av.x; As[lc4 + 1][lrow] = av.y;
        As[lc4 + 2][lrow] = av.z; As[lc4 + 3][lrow] = av.w;
        const float4 wv = *(const float4*)&W[(size_t)(k0 + brow) * N + n0 + bc4];
        *(float4*)&Bs[brow][bc4] = wv;
        __syncthreads();
        #pragma unroll
        for (int kk = 0; kk < TK; ++kk) {
            const float4 a4 = *(const float4*)&As[kk][ty * 4];
            const float4 b4 = *(const float4*)&Bs[kk][tx * 4];
            const float a[4] = {a4.x, a4.y, a4.z, a4.w};
            const float b[4] = {b4.x, b4.y, b4.z, b4.w};
            #pragma unroll
            for (int i = 0; i < 4; ++i)
                #pragma unroll
                for (int j = 0; j < 4; ++j)
                    acc[i][j] = fmaf(a[i], b[j], acc[i][j]);
        }
        __syncthreads();
    }
    #pragma unroll
    for (int i = 0; i < 4; ++i) {
        *(float4*)&C[(size_t)(m0 + ty * 4 + i) * N + n0 + tx * 4] =
            make_float4(acc[i][0], acc[i][1], acc[i][2], acc[i][3]);
    }
}

// Flash-style MQA attention: one thread owns one (b, h, n) query row.
// q_buf [B,N,H*64], k_buf/v_buf [B,M,64], o_buf [B,N,H*64].
__global__ __launch_bounds__(256) void attn_kernel(
    const float* __restrict__ q_buf, const float* __restrict__ k_buf,
    const float* __restrict__ v_buf, float* __restrict__ o_buf)
{
    constexpr int NN = 2048, HH = 16, DK = 64;
    __shared__ alignas(16) float Ks[64][DK];
    __shared__ alignas(16) float Vs[64][DK];
    const int ntiles = NN / 256;               // 8
    const int wg  = blockIdx.x;                // 0..B*H*ntiles-1
    const int b   = wg / (HH * ntiles);
    const int rem = wg % (HH * ntiles);
    const int h   = rem / ntiles;
    const int n   = (rem % ntiles) * 256 + threadIdx.x;

    float qr[DK];
    {
        const float* qp = &q_buf[((size_t)(b * NN + n) * HH + h) * DK];
        #pragma unroll
        for (int i = 0; i < DK / 4; ++i) {
            const float4 v4 = *(const float4*)&qp[4 * i];
            qr[4*i+0] = v4.x; qr[4*i+1] = v4.y; qr[4*i+2] = v4.z; qr[4*i+3] = v4.w;
        }
    }
    float o[DK] = {};
    float mx = -1e30f, lsum = 0.f;

    for (int m0 = 0; m0 < NN; m0 += 64) {
        __syncthreads();   // protect previous tile's reads
        #pragma unroll
        for (int i = 0; i < 4; ++i) {
            const int idx = threadIdx.x + i * 256;   // 0..1023 float4 slots
            const int row = idx >> 4;
            const int c4  = (idx & 15) << 2;
            *(float4*)&Ks[row][c4] = *(const float4*)&k_buf[(size_t)(b * NN + m0 + row) * DK + c4];
            *(float4*)&Vs[row][c4] = *(const float4*)&v_buf[(size_t)(b * NN + m0 + row) * DK + c4];
        }
        __syncthreads();
        for (int mm = 0; mm < 64; ++mm) {
            float s = 0.f;
            #pragma unroll
            for (int i = 0; i < DK / 4; ++i) {
                const float4 kv = *(const float4*)&Ks[mm][4 * i];
                s = fmaf(qr[4*i+0], kv.x, s);
                s = fmaf(qr[4*i+1], kv.y, s);
                s = fmaf(qr[4*i+2], kv.z, s);
                s = fmaf(qr[4*i+3], kv.w, s);
            }
            s *= 0.125f;   // 1/sqrt(64)
            if (s > mx) {  // rare after warm-up: rescale state
                const float corr = __expf(mx - s);   // first iter: exp(-huge)=0
                lsum *= corr;
                #pragma unroll
                for (int j = 0; j < DK; ++j) o[j] *= corr;
                mx = s;
            }
            const float p = __expf(s - mx);
            lsum += p;
            #pragma unroll
            for (int i = 0; i < DK / 4; ++i) {
                const float4 vv = *(const float4*)&Vs[mm][4 * i];
                o[4*i+0] = fmaf(p, vv.x, o[4*i+0]);
                o[4*i+1] = fmaf(p, vv.y, o[4*i+1]);
                o[4*i+2] = fmaf(p, vv.z, o[4*i+2]);
                o[4*i+3] = fmaf(p, vv.w, o[4*i+3]);
            }
        }
    }
    const float inv = 1.f / lsum;
    float* outp = &o_buf[((size_t)(b * NN + n) * HH + h) * DK];
    #pragma unroll
    for (int i = 0; i < DK / 4; ++i) {
        *(float4*)&outp[4 * i] =
            make_float4(o[4*i+0] * inv, o[4*i+1] * inv, o[4*i+2] * inv, o[4*i+3] * inv);
    }
}

extern "C" void kernel_launch(void* const* d_in, const int* in_sizes, int n_in,
                              void* d_out, int out_size, void* d_ws, size_t ws_size,
                              hipStream_t stream)
{
    const float* x  = (const float*)d_in[0];  // [2,2048,1024]
    const float* qp = (const float*)d_in[1];  // [16,64,1024]  -> W[hk][d]
    const float* kp = (const float*)d_in[2];  // [1024,64]
    const float* vp = (const float*)d_in[3];  // [1024,64]
    const float* op = (const float*)d_in[4];  // [1024,16,64]  -> W[d][hv]
    float* out = (float*)d_out;               // [2,2048,1024]
    float* ws  = (float*)d_ws;

    float* q_buf = ws;                  // 4096*1024 floats
    float* o_buf = ws + 4194304;        // 4096*1024
    float* k_buf = ws + 8388608;        // 4096*64
    float* v_buf = ws + 8650752;        // 4096*64

    const int M = 4096, D = 1024, HK = 1024;

    // q = x @ query_proj^T  (per-head, fused as one 1024-col GEMM)
    hipLaunchKernelGGL(gemm_bt_kernel, dim3(HK / TILE, M / TILE), dim3(256), 0, stream,
                       x, qp, q_buf, M, HK, D);
    // k = x @ key_proj ; v = x @ value_proj
    hipLaunchKernelGGL(gemm_bn_kernel, dim3(1, M / TILE), dim3(256), 0, stream,
                       x, kp, k_buf, M, 64, D);
    hipLaunchKernelGGL(gemm_bn_kernel, dim3(1, M / TILE), dim3(256), 0, stream,
                       x, vp, v_buf, M, 64, D);
    // o = softmax(q k^T / 8) v
    hipLaunchKernelGGL(attn_kernel, dim3(2 * 16 * 2048 / 256), dim3(256), 0, stream,
                       q_buf, k_buf, v_buf, o_buf);
    // out = o @ output_proj^T (over hv)
    hipLaunchKernelGGL(gemm_bt_kernel, dim3(D / TILE, M / TILE), dim3(256), 0, stream,
                       o_buf, op, out, M, D, HK);
}

// Round 2
// 556.644 us; speedup vs baseline: 2.7637x; 2.7637x over previous
//
#include <hip/hip_runtime.h>
#include <math.h>

// Problem constants: B=2, N=2048, D=1024, H=16, K=V=64
#define TK 16
#define TILE 64
#define LDSP 68   // fp32 GEMM LDS pad

typedef __bf16 bf16x8 __attribute__((ext_vector_type(8)));
typedef float  f32x4  __attribute__((ext_vector_type(4)));

static __device__ __forceinline__ ushort f2bf(float f) {
    // round-to-nearest-even fp32 -> bf16 bits
    unsigned u = __float_as_uint(f);
    unsigned r = (u + 0x7fffu + ((u >> 16) & 1u)) >> 16;
    return (ushort)r;
}

// ---------------- fp32 GEMM, C = A[M][K] * W[N][K]^T, fp32 out ----------------
__global__ __launch_bounds__(256) void gemm_bt_kernel(
    const float* __restrict__ A, const float* __restrict__ W,
    float* __restrict__ C, int M, int N, int K)
{
    __shared__ alignas(16) float As[TK][LDSP];
    __shared__ alignas(16) float Bs[TK][LDSP];
    const int t  = threadIdx.x;
    const int tx = t & 15, ty = t >> 4;
    const int m0 = blockIdx.y * TILE;
    const int n0 = blockIdx.x * TILE;
    const int lrow = t >> 2;
    const int lc4  = (t & 3) << 2;
    float acc[4][4] = {};
    for (int k0 = 0; k0 < K; k0 += TK) {
        const float4 av = *(const float4*)&A[(size_t)(m0 + lrow) * K + k0 + lc4];
        const float4 wv = *(const float4*)&W[(size_t)(n0 + lrow) * K + k0 + lc4];
        As[lc4 + 0][lrow] = av.x; As[lc4 + 1][lrow] = av.y;
        As[lc4 + 2][lrow] = av.z; As[lc4 + 3][lrow] = av.w;
        Bs[lc4 + 0][lrow] = wv.x; Bs[lc4 + 1][lrow] = wv.y;
        Bs[lc4 + 2][lrow] = wv.z; Bs[lc4 + 3][lrow] = wv.w;
        __syncthreads();
        #pragma unroll
        for (int kk = 0; kk < TK; ++kk) {
            const float4 a4 = *(const float4*)&As[kk][ty * 4];
            const float4 b4 = *(const float4*)&Bs[kk][tx * 4];
            const float a[4] = {a4.x, a4.y, a4.z, a4.w};
            const float b[4] = {b4.x, b4.y, b4.z, b4.w};
            #pragma unroll
            for (int i = 0; i < 4; ++i)
                #pragma unroll
                for (int j = 0; j < 4; ++j)
                    acc[i][j] = fmaf(a[i], b[j], acc[i][j]);
        }
        __syncthreads();
    }
    #pragma unroll
    for (int i = 0; i < 4; ++i)
        *(float4*)&C[(size_t)(m0 + ty * 4 + i) * N + n0 + tx * 4] =
            make_float4(acc[i][0], acc[i][1], acc[i][2], acc[i][3]);
}

// ------------- fp32 GEMM, C = A[M][K] * W[N][K]^T, bf16 out (q-proj) -------------
__global__ __launch_bounds__(256) void gemm_bt_bf16_kernel(
    const float* __restrict__ A, const float* __restrict__ W,
    ushort* __restrict__ C, int M, int N, int K)
{
    __shared__ alignas(16) float As[TK][LDSP];
    __shared__ alignas(16) float Bs[TK][LDSP];
    const int t  = threadIdx.x;
    const int tx = t & 15, ty = t >> 4;
    const int m0 = blockIdx.y * TILE;
    const int n0 = blockIdx.x * TILE;
    const int lrow = t >> 2;
    const int lc4  = (t & 3) << 2;
    float acc[4][4] = {};
    for (int k0 = 0; k0 < K; k0 += TK) {
        const float4 av = *(const float4*)&A[(size_t)(m0 + lrow) * K + k0 + lc4];
        const float4 wv = *(const float4*)&W[(size_t)(n0 + lrow) * K + k0 + lc4];
        As[lc4 + 0][lrow] = av.x; As[lc4 + 1][lrow] = av.y;
        As[lc4 + 2][lrow] = av.z; As[lc4 + 3][lrow] = av.w;
        Bs[lc4 + 0][lrow] = wv.x; Bs[lc4 + 1][lrow] = wv.y;
        Bs[lc4 + 2][lrow] = wv.z; Bs[lc4 + 3][lrow] = wv.w;
        __syncthreads();
        #pragma unroll
        for (int kk = 0; kk < TK; ++kk) {
            const float4 a4 = *(const float4*)&As[kk][ty * 4];
            const float4 b4 = *(const float4*)&Bs[kk][tx * 4];
            const float a[4] = {a4.x, a4.y, a4.z, a4.w};
            const float b[4] = {b4.x, b4.y, b4.z, b4.w};
            #pragma unroll
            for (int i = 0; i < 4; ++i)
                #pragma unroll
                for (int j = 0; j < 4; ++j)
                    acc[i][j] = fmaf(a[i], b[j], acc[i][j]);
        }
        __syncthreads();
    }
    #pragma unroll
    for (int i = 0; i < 4; ++i) {
        ushort4 s;
        s.x = f2bf(acc[i][0]); s.y = f2bf(acc[i][1]);
        s.z = f2bf(acc[i][2]); s.w = f2bf(acc[i][3]);
        *(ushort4*)&C[(size_t)(m0 + ty * 4 + i) * N + n0 + tx * 4] = s;
    }
}

// ---- fp32 GEMM, C = A[M][64] path for K/V proj, bf16 out, optional transpose ----
// TRANS=false: C[m][n] bf16 (k_bf).  TRANS=true: C_t[b][n][m%2048] bf16 (v transposed).
template <bool TRANS>
__global__ __launch_bounds__(256) void gemm_bn_bf16_kernel(
    const float* __restrict__ A, const float* __restrict__ W,
    ushort* __restrict__ C, int M, int N, int K)
{
    __shared__ alignas(16) float As[TK][LDSP];
    __shared__ alignas(16) float Bs[TK][LDSP];
    const int t  = threadIdx.x;
    const int tx = t & 15, ty = t >> 4;
    const int m0 = blockIdx.y * TILE;
    const int n0 = blockIdx.x * TILE;
    const int lrow = t >> 2;
    const int lc4  = (t & 3) << 2;
    const int brow = t >> 4;
    const int bc4  = (t & 15) << 2;
    float acc[4][4] = {};
    for (int k0 = 0; k0 < K; k0 += TK) {
        const float4 av = *(const float4*)&A[(size_t)(m0 + lrow) * K + k0 + lc4];
        As[lc4 + 0][lrow] = av.x; As[lc4 + 1][lrow] = av.y;
        As[lc4 + 2][lrow] = av.z; As[lc4 + 3][lrow] = av.w;
        const float4 wv = *(const float4*)&W[(size_t)(k0 + brow) * N + n0 + bc4];
        *(float4*)&Bs[brow][bc4] = wv;
        __syncthreads();
        #pragma unroll
        for (int kk = 0; kk < TK; ++kk) {
            const float4 a4 = *(const float4*)&As[kk][ty * 4];
            const float4 b4 = *(const float4*)&Bs[kk][tx * 4];
            const float a[4] = {a4.x, a4.y, a4.z, a4.w};
            const float b[4] = {b4.x, b4.y, b4.z, b4.w};
            #pragma unroll
            for (int i = 0; i < 4; ++i)
                #pragma unroll
                for (int j = 0; j < 4; ++j)
                    acc[i][j] = fmaf(a[i], b[j], acc[i][j]);
        }
        __syncthreads();
    }
    #pragma unroll
    for (int i = 0; i < 4; ++i) {
        const int mrow = m0 + ty * 4 + i;
        if (!TRANS) {
            ushort4 s;
            s.x = f2bf(acc[i][0]); s.y = f2bf(acc[i][1]);
            s.z = f2bf(acc[i][2]); s.w = f2bf(acc[i][3]);
            *(ushort4*)&C[(size_t)mrow * N + n0 + tx * 4] = s;
        } else {
            const int b  = mrow >> 11;
            const int kv = mrow & 2047;
            #pragma unroll
            for (int j = 0; j < 4; ++j)
                C[(size_t)b * 64 * 2048 + (size_t)(n0 + tx * 4 + j) * 2048 + kv] = f2bf(acc[i][j]);
        }
    }
}

// ---------------- bf16 MFMA flash attention ----------------
// grid: B*H*(N/128) blocks, 256 threads (4 waves); wave owns 32 q-rows.
// q_bf [B*N][H*64], k_bf [B*N][64], vt_bf [B][64][N], o_buf fp32 [B*N][H*64].
#define KSTR 72   // LDS row stride in bf16 elems: 144B (16B-aligned, <=2-way banks)

__global__ __launch_bounds__(256) void attn_mfma_kernel(
    const ushort* __restrict__ q_bf, const ushort* __restrict__ k_bf,
    const ushort* __restrict__ vt_bf, float* __restrict__ o_buf)
{
    constexpr int NN = 2048, HH = 16;
    __shared__ ushort Ks[64][KSTR];       // K tile  [kv][dk]
    __shared__ ushort Vs[64][KSTR];       // V^T tile [vd][kv]
    __shared__ ushort Ps[4][32][KSTR];    // per-wave P [q][kv]

    const int wgid = blockIdx.x;
    const int qt = wgid & 15;
    const int h  = (wgid >> 4) & 15;
    const int b  = wgid >> 8;
    const int t  = threadIdx.x;
    const int w  = t >> 6;      // wave
    const int l  = t & 63;
    const int lg = l >> 4;      // 4-lane-group id 0..3
    const int ll = l & 15;

    const int q0 = qt * 128 + w * 32;   // wave's q-row base within (b,h)

    // Q fragments, resident all kernel: qf[mt][ks]
    bf16x8 qf[2][2];
    #pragma unroll
    for (int mt = 0; mt < 2; ++mt) {
        const size_t base = ((size_t)(b * NN) + q0 + mt * 16 + ll) * (HH * 64) + h * 64;
        #pragma unroll
        for (int ks = 0; ks < 2; ++ks) {
            uint4 u = *(const uint4*)&q_bf[base + ks * 32 + lg * 8];
            qf[mt][ks] = __builtin_bit_cast(bf16x8, u);
        }
    }

    f32x4 Ofrag[2][4] = {};
    float m_run[2][4], l_run[2][4];
    #pragma unroll
    for (int mt = 0; mt < 2; ++mt)
        #pragma unroll
        for (int r = 0; r < 4; ++r) { m_run[mt][r] = -1e30f; l_run[mt][r] = 0.f; }

    for (int kv0 = 0; kv0 < NN; kv0 += 64) {
        __syncthreads();
        // stage K tile and V^T tile (bf16, already converted)
        #pragma unroll
        for (int i = 0; i < 2; ++i) {
            const int c   = t + i * 256;        // 0..511 16B-chunks
            const int row = c >> 3;
            const int c8  = (c & 7) * 8;
            uint4 kk4 = *(const uint4*)&k_bf[((size_t)(b * NN) + kv0 + row) * 64 + c8];
            *(uint4*)&Ks[row][c8] = kk4;
            uint4 vv4 = *(const uint4*)&vt_bf[(size_t)b * 64 * NN + (size_t)row * NN + kv0 + c8];
            *(uint4*)&Vs[row][c8] = vv4;
        }
        __syncthreads();

        // S = Q K^T  (A rows=q, B cols=kv, k-dim = dk)
        f32x4 S[2][4] = {};
        #pragma unroll
        for (int ks = 0; ks < 2; ++ks) {
            bf16x8 kf[4];
            #pragma unroll
            for (int nt = 0; nt < 4; ++nt)
                kf[nt] = __builtin_bit_cast(bf16x8, *(const uint4*)&Ks[nt * 16 + ll][ks * 32 + lg * 8]);
            #pragma unroll
            for (int mt = 0; mt < 2; ++mt)
                #pragma unroll
                for (int nt = 0; nt < 4; ++nt)
                    S[mt][nt] = __builtin_amdgcn_mfma_f32_16x16x32_bf16(qf[mt][ks], kf[nt], S[mt][nt], 0, 0, 0);
        }

        // online softmax (fp32), P -> wave-private LDS as bf16
        #pragma unroll
        for (int mt = 0; mt < 2; ++mt) {
            #pragma unroll
            for (int r = 0; r < 4; ++r) {
                float s0 = S[mt][0][r] * 0.125f, s1 = S[mt][1][r] * 0.125f;
                float s2 = S[mt][2][r] * 0.125f, s3 = S[mt][3][r] * 0.125f;
                float mx = fmaxf(fmaxf(s0, s1), fmaxf(s2, s3));
                mx = fmaxf(mx, __shfl_xor(mx, 1, 16));
                mx = fmaxf(mx, __shfl_xor(mx, 2, 16));
                mx = fmaxf(mx, __shfl_xor(mx, 4, 16));
                mx = fmaxf(mx, __shfl_xor(mx, 8, 16));
                const float mnew = fmaxf(m_run[mt][r], mx);
                const float corr = __expf(m_run[mt][r] - mnew);
                m_run[mt][r] = mnew;
                const float p0 = __expf(s0 - mnew), p1 = __expf(s1 - mnew);
                const float p2 = __expf(s2 - mnew), p3 = __expf(s3 - mnew);
                float ps = p0 + p1 + p2 + p3;
                ps += __shfl_xor(ps, 1, 16);
                ps += __shfl_xor(ps, 2, 16);
                ps += __shfl_xor(ps, 4, 16);
                ps += __shfl_xor(ps, 8, 16);
                l_run[mt][r] = l_run[mt][r] * corr + ps;
                #pragma unroll
                for (int nt = 0; nt < 4; ++nt) Ofrag[mt][nt][r] *= corr;
                const int prow = mt * 16 + lg * 4 + r;
                Ps[w][prow][0 * 16 + ll] = f2bf(p0);
                Ps[w][prow][1 * 16 + ll] = f2bf(p1);
                Ps[w][prow][2 * 16 + ll] = f2bf(p2);
                Ps[w][prow][3 * 16 + ll] = f2bf(p3);
            }
        }

        // O += P V   (A rows=q k-dim=kv; B cols=vd from V^T tile)
        #pragma unroll
        for (int ks = 0; ks < 2; ++ks) {
            bf16x8 pf[2], vf[4];
            #pragma unroll
            for (int mt = 0; mt < 2; ++mt)
                pf[mt] = __builtin_bit_cast(bf16x8, *(const uint4*)&Ps[w][mt * 16 + ll][ks * 32 + lg * 8]);
            #pragma unroll
            for (int nt = 0; nt < 4; ++nt)
                vf[nt] = __builtin_bit_cast(bf16x8, *(const uint4*)&Vs[nt * 16 + ll][ks * 32 + lg * 8]);
            #pragma unroll
            for (int mt = 0; mt < 2; ++mt)
                #pragma unroll
                for (int nt = 0; nt < 4; ++nt)
                    Ofrag[mt][nt] = __builtin_amdgcn_mfma_f32_16x16x32_bf16(pf[mt], vf[nt], Ofrag[mt][nt], 0, 0, 0);
        }
    }

    // epilogue: divide by l, store fp32 O
    #pragma unroll
    for (int mt = 0; mt < 2; ++mt) {
        #pragma unroll
        for (int r = 0; r < 4; ++r) {
            const float inv = 1.0f / l_run[mt][r];
            const int qrow = q0 + mt * 16 + lg * 4 + r;
            float* dst = &o_buf[((size_t)(b * NN) + qrow) * (HH * 64) + h * 64];
            #pragma unroll
            for (int nt = 0; nt < 4; ++nt)
                dst[nt * 16 + ll] = Ofrag[mt][nt][r] * inv;
        }
    }
}

extern "C" void kernel_launch(void* const* d_in, const int* in_sizes, int n_in,
                              void* d_out, int out_size, void* d_ws, size_t ws_size,
                              hipStream_t stream)
{
    const float* x  = (const float*)d_in[0];  // [2,2048,1024]
    const float* qp = (const float*)d_in[1];  // [16,64,1024] -> [1024][1024] rows hk
    const float* kp = (const float*)d_in[2];  // [1024,64]
    const float* vp = (const float*)d_in[3];  // [1024,64]
    const float* op = (const float*)d_in[4];  // [1024,16,64] -> [1024][1024] rows d
    float* out = (float*)d_out;               // [2,2048,1024]

    char* ws = (char*)d_ws;
    ushort* q_bf  = (ushort*)(ws);                    // 4096*1024 bf16 = 8 MB
    ushort* k_bf  = (ushort*)(ws + 8388608);          // 4096*64   bf16 = 512 KB
    ushort* vt_bf = (ushort*)(ws + 8912896);          // 2*64*2048 bf16 = 512 KB
    float*  o_buf = (float*)(ws + 9437184);           // 4096*1024 f32  = 16 MB

    const int M = 4096, D = 1024, HK = 1024;

    // q = x @ query_proj^T  -> bf16 [4096][1024]
    gemm_bt_bf16_kernel<<<dim3(HK / TILE, M / TILE), 256, 0, stream>>>(x, qp, q_bf, M, HK, D);
    // k = x @ key_proj -> bf16 [4096][64] ; v = x @ value_proj -> bf16 transposed [2][64][2048]
    gemm_bn_bf16_kernel<false><<<dim3(1, M / TILE), 256, 0, stream>>>(x, kp, k_bf, M, 64, D);
    gemm_bn_bf16_kernel<true ><<<dim3(1, M / TILE), 256, 0, stream>>>(x, vp, vt_bf, M, 64, D);
    // o = softmax(q k^T / 8) v   (bf16 MFMA, fp32 accum)
    attn_mfma_kernel<<<dim3(2 * 16 * 16), 256, 0, stream>>>(q_bf, k_bf, vt_bf, o_buf);
    // out = o @ output_proj^T  (fp32)
    gemm_bt_kernel<<<dim3(D / TILE, M / TILE), 256, 0, stream>>>(o_buf, op, out, M, D, HK);
}

// Round 3
// 249.325 us; speedup vs baseline: 6.1702x; 2.2326x over previous
//
#include <hip/hip_runtime.h>
#include <math.h>

// Problem constants: B=2, N=2048, D=1024, H=16, K=V=64
typedef __bf16  bf16x8  __attribute__((ext_vector_type(8)));
typedef float   f32x4   __attribute__((ext_vector_type(4)));
typedef ushort  u16x8   __attribute__((ext_vector_type(8)));

static __device__ __forceinline__ ushort f2bf(float f) {
    unsigned u = __float_as_uint(f);
    unsigned r = (u + 0x7fffu + ((u >> 16) & 1u)) >> 16;   // RNE
    return (ushort)r;
}

// async global->LDS, 16B per lane (dest must be linear in lane index)
static __device__ __forceinline__ void gload_lds16(const ushort* g, ushort* l) {
    __builtin_amdgcn_global_load_lds(
        (const __attribute__((address_space(1))) unsigned int*)g,
        (__attribute__((address_space(3))) unsigned int*)l, 16, 0, 0);
}

// ---------------- convert: fp32 -> bf16, pack weights ----------------
// wall[1152][1024]: rows 0..1023 = query_proj (hk-major, already B^T);
//                   rows 1024..1087 = key_proj^T; rows 1088..1151 = value_proj^T
__global__ __launch_bounds__(256) void convert_kernel(
    const float* __restrict__ x, const float* __restrict__ qp,
    const float* __restrict__ kp, const float* __restrict__ vp,
    const float* __restrict__ op,
    ushort* __restrict__ x_bf, ushort* __restrict__ wall_bf,
    ushort* __restrict__ op_bf)
{
    const int bid = blockIdx.x, t = threadIdx.x;
    if (bid < 4096) {                       // x: 1M float4
        const int i = bid * 256 + t;
        const float4 v = ((const float4*)x)[i];
        ushort4 s; s.x = f2bf(v.x); s.y = f2bf(v.y); s.z = f2bf(v.z); s.w = f2bf(v.w);
        ((ushort4*)x_bf)[i] = s;
    } else if (bid < 5120) {                // qp -> wall rows 0..1023: 256K float4
        const int i = (bid - 4096) * 256 + t;
        const float4 v = ((const float4*)qp)[i];
        ushort4 s; s.x = f2bf(v.x); s.y = f2bf(v.y); s.z = f2bf(v.z); s.w = f2bf(v.w);
        ((ushort4*)wall_bf)[i] = s;
    } else if (bid < 6144) {                // op -> op_bf: 256K float4
        const int i = (bid - 5120) * 256 + t;
        const float4 v = ((const float4*)op)[i];
        ushort4 s; s.x = f2bf(v.x); s.y = f2bf(v.y); s.z = f2bf(v.z); s.w = f2bf(v.w);
        ((ushort4*)op_bf)[i] = s;
    } else if (bid < 6400) {                // kp^T -> wall rows 1024..1087
        const int i = (bid - 6144) * 256 + t;     // i = k*1024 + d
        const int k = i >> 10, d = i & 1023;
        wall_bf[(size_t)(1024 + k) * 1024 + d] = f2bf(kp[(size_t)d * 64 + k]);
    } else {                                // vp^T -> wall rows 1088..1151
        const int i = (bid - 6400) * 256 + t;
        const int v = i >> 10, d = i & 1023;
        wall_bf[(size_t)(1088 + v) * 1024 + d] = f2bf(vp[(size_t)d * 64 + v]);
    }
}

// ---------------- bf16 MFMA GEMM: C[M][N] = A[M][K] * Bt[N][K]^T ----------------
// 128x128 tile, BK=32, 4 waves (2x2), global_load_lds staging with XOR chunk swizzle.
template <bool OUT_BF16>
__global__ __launch_bounds__(256) void gemm_mfma_bt(
    const ushort* __restrict__ A, const ushort* __restrict__ Bt,
    void* __restrict__ Cv, int M, int N, int K)
{
    __shared__ alignas(16) ushort Asm[128 * 32];
    __shared__ alignas(16) ushort Bsm[128 * 32];
    const int t  = threadIdx.x;
    const int w  = t >> 6, l = t & 63;
    const int ll = l & 15, lg = l >> 4;
    const int wr = w >> 1, wc = w & 1;
    const int m0 = blockIdx.y * 128, n0 = blockIdx.x * 128;

    f32x4 acc[4][4] = {};

    for (int k0 = 0; k0 < K; k0 += 32) {
        __syncthreads();   // prior iteration's LDS reads complete
        #pragma unroll
        for (int i = 0; i < 2; ++i) {
            const int c   = t + i * 256;          // 0..511 16B chunks
            const int row = c >> 2, p = c & 3;
            const int gp  = p ^ ((row >> 1) & 3); // source pre-swizzle
            gload_lds16(&A [(size_t)(m0 + row) * K + k0 + gp * 8], &Asm[c * 8]);
            gload_lds16(&Bt[(size_t)(n0 + row) * K + k0 + gp * 8], &Bsm[c * 8]);
        }
        asm volatile("s_waitcnt vmcnt(0)" ::: "memory");
        __syncthreads();

        bf16x8 af[4], bfr[4];
        #pragma unroll
        for (int mt = 0; mt < 4; ++mt) {
            const int r = wr * 64 + mt * 16 + ll;
            af[mt] = *(const bf16x8*)&Asm[r * 32 + (lg ^ ((r >> 1) & 3)) * 8];
        }
        #pragma unroll
        for (int nt = 0; nt < 4; ++nt) {
            const int r = wc * 64 + nt * 16 + ll;
            bfr[nt] = *(const bf16x8*)&Bsm[r * 32 + (lg ^ ((r >> 1) & 3)) * 8];
        }
        #pragma unroll
        for (int mt = 0; mt < 4; ++mt)
            #pragma unroll
            for (int nt = 0; nt < 4; ++nt)
                acc[mt][nt] = __builtin_amdgcn_mfma_f32_16x16x32_bf16(af[mt], bfr[nt], acc[mt][nt], 0, 0, 0);
    }

    // epilogue: C/D layout col=lane&15, row=(lane>>4)*4+reg
    #pragma unroll
    for (int mt = 0; mt < 4; ++mt) {
        #pragma unroll
        for (int r = 0; r < 4; ++r) {
            const size_t row = m0 + wr * 64 + mt * 16 + lg * 4 + r;
            #pragma unroll
            for (int nt = 0; nt < 4; ++nt) {
                const size_t col = n0 + wc * 64 + nt * 16 + ll;
                if (OUT_BF16) ((ushort*)Cv)[row * N + col] = f2bf(acc[mt][nt][r]);
                else          ((float *)Cv)[row * N + col] = acc[mt][nt][r];
            }
        }
    }
}

// ---------------- V^T build: vt[b][vd][m] from qkv cols 1088..1151 ----------------
__global__ __launch_bounds__(256) void transpose_v_kernel(
    const ushort* __restrict__ qkv, ushort* __restrict__ vt_bf)
{
    __shared__ alignas(16) ushort tl[64][72];
    const int b  = blockIdx.x >> 5;
    const int m0 = (blockIdx.x & 31) * 64;
    const int t  = threadIdx.x;
    #pragma unroll
    for (int i = 0; i < 2; ++i) {
        const int c = t + i * 256, row = c >> 3, p = c & 7;
        const uint4 v4 = *(const uint4*)&qkv[(size_t)(b * 2048 + m0 + row) * 1152 + 1088 + p * 8];
        const u16x8 v = __builtin_bit_cast(u16x8, v4);
        #pragma unroll
        for (int j = 0; j < 8; ++j) tl[p * 8 + j][row] = v[j];
    }
    __syncthreads();
    #pragma unroll
    for (int i = 0; i < 2; ++i) {
        const int c = t + i * 256, vd = c >> 3, p = c & 7;
        *(uint4*)&vt_bf[(size_t)b * 64 * 2048 + (size_t)vd * 2048 + m0 + p * 8] =
            *(const uint4*)&tl[vd][p * 8];
    }
}

// ---------------- bf16 MFMA flash attention ----------------
// grid: B*H*(N/64) = 1024 blocks, 4 waves; wave owns 16 q-rows.
// qkv [B*N][1152] (q cols 0..1023 h-major, k cols 1024..1087), vt [B][64][N], o bf16 [B*N][1024]
#define KSTR 72
__global__ __launch_bounds__(256) void attn_mfma_kernel(
    const ushort* __restrict__ qkv, const ushort* __restrict__ vt_bf,
    ushort* __restrict__ o_bf)
{
    constexpr int NN = 2048;
    __shared__ alignas(16) ushort Ks[64][KSTR];
    __shared__ alignas(16) ushort Vs[64][KSTR];
    __shared__ alignas(16) ushort Ps[4][16][KSTR];

    const int qt = blockIdx.x & 31;
    const int h  = (blockIdx.x >> 5) & 15;
    const int b  = blockIdx.x >> 9;
    const int t  = threadIdx.x;
    const int w  = t >> 6, l = t & 63;
    const int lg = l >> 4, ll = l & 15;
    const int q0 = qt * 64 + w * 16;

    bf16x8 qf[2];
    {
        const size_t base = ((size_t)(b * NN) + q0 + ll) * 1152 + h * 64;
        #pragma unroll
        for (int ks = 0; ks < 2; ++ks)
            qf[ks] = __builtin_bit_cast(bf16x8, *(const uint4*)&qkv[base + ks * 32 + lg * 8]);
    }

    f32x4 Ofrag[4] = {};
    float m_run[4], l_run[4];
    #pragma unroll
    for (int r = 0; r < 4; ++r) { m_run[r] = -1e30f; l_run[r] = 0.f; }

    for (int kv0 = 0; kv0 < NN; kv0 += 64) {
        __syncthreads();
        #pragma unroll
        for (int i = 0; i < 2; ++i) {
            const int c = t + i * 256, row = c >> 3, c8 = (c & 7) * 8;
            *(uint4*)&Ks[row][c8] =
                *(const uint4*)&qkv[((size_t)(b * NN) + kv0 + row) * 1152 + 1024 + c8];
            *(uint4*)&Vs[row][c8] =
                *(const uint4*)&vt_bf[(size_t)b * 64 * NN + (size_t)row * NN + kv0 + c8];
        }
        __syncthreads();

        f32x4 S[4] = {};
        #pragma unroll
        for (int ks = 0; ks < 2; ++ks) {
            bf16x8 kf[4];
            #pragma unroll
            for (int nt = 0; nt < 4; ++nt)
                kf[nt] = __builtin_bit_cast(bf16x8, *(const uint4*)&Ks[nt * 16 + ll][ks * 32 + lg * 8]);
            #pragma unroll
            for (int nt = 0; nt < 4; ++nt)
                S[nt] = __builtin_amdgcn_mfma_f32_16x16x32_bf16(qf[ks], kf[nt], S[nt], 0, 0, 0);
        }

        #pragma unroll
        for (int r = 0; r < 4; ++r) {
            float s0 = S[0][r] * 0.125f, s1 = S[1][r] * 0.125f;
            float s2 = S[2][r] * 0.125f, s3 = S[3][r] * 0.125f;
            float mx = fmaxf(fmaxf(s0, s1), fmaxf(s2, s3));
            mx = fmaxf(mx, __shfl_xor(mx, 1, 16));
            mx = fmaxf(mx, __shfl_xor(mx, 2, 16));
            mx = fmaxf(mx, __shfl_xor(mx, 4, 16));
            mx = fmaxf(mx, __shfl_xor(mx, 8, 16));
            const float mnew = fmaxf(m_run[r], mx);
            const float corr = __expf(m_run[r] - mnew);
            m_run[r] = mnew;
            const float p0 = __expf(s0 - mnew), p1 = __expf(s1 - mnew);
            const float p2 = __expf(s2 - mnew), p3 = __expf(s3 - mnew);
            float ps = p0 + p1 + p2 + p3;
            ps += __shfl_xor(ps, 1, 16);
            ps += __shfl_xor(ps, 2, 16);
            ps += __shfl_xor(ps, 4, 16);
            ps += __shfl_xor(ps, 8, 16);
            l_run[r] = l_run[r] * corr + ps;
            #pragma unroll
            for (int nt = 0; nt < 4; ++nt) Ofrag[nt][r] *= corr;
            const int prow = lg * 4 + r;
            Ps[w][prow][0 * 16 + ll] = f2bf(p0);
            Ps[w][prow][1 * 16 + ll] = f2bf(p1);
            Ps[w][prow][2 * 16 + ll] = f2bf(p2);
            Ps[w][prow][3 * 16 + ll] = f2bf(p3);
        }

        #pragma unroll
        for (int ks = 0; ks < 2; ++ks) {
            bf16x8 pf, vf[4];
            pf = __builtin_bit_cast(bf16x8, *(const uint4*)&Ps[w][ll][ks * 32 + lg * 8]);
            #pragma unroll
            for (int nt = 0; nt < 4; ++nt)
                vf[nt] = __builtin_bit_cast(bf16x8, *(const uint4*)&Vs[nt * 16 + ll][ks * 32 + lg * 8]);
            #pragma unroll
            for (int nt = 0; nt < 4; ++nt)
                Ofrag[nt] = __builtin_amdgcn_mfma_f32_16x16x32_bf16(pf, vf[nt], Ofrag[nt], 0, 0, 0);
        }
    }

    #pragma unroll
    for (int r = 0; r < 4; ++r) {
        const float inv = 1.0f / l_run[r];
        const size_t qrow = (size_t)(b * NN) + q0 + lg * 4 + r;
        #pragma unroll
        for (int nt = 0; nt < 4; ++nt)
            o_bf[qrow * 1024 + h * 64 + nt * 16 + ll] = f2bf(Ofrag[nt][r] * inv);
    }
}

extern "C" void kernel_launch(void* const* d_in, const int* in_sizes, int n_in,
                              void* d_out, int out_size, void* d_ws, size_t ws_size,
                              hipStream_t stream)
{
    const float* x  = (const float*)d_in[0];
    const float* qp = (const float*)d_in[1];
    const float* kp = (const float*)d_in[2];
    const float* vp = (const float*)d_in[3];
    const float* op = (const float*)d_in[4];
    float* out = (float*)d_out;

    char* ws = (char*)d_ws;
    ushort* x_bf    = (ushort*)(ws);                 //  8,388,608 B
    ushort* wall_bf = (ushort*)(ws + 8388608);       //  2,359,296 B [1152][1024]
    ushort* op_bf   = (ushort*)(ws + 10747904);      //  2,097,152 B
    ushort* qkv     = (ushort*)(ws + 12845056);      //  9,437,184 B [4096][1152]
    ushort* vt_bf   = (ushort*)(ws + 22282240);      //    524,288 B [2][64][2048]
    ushort* o_bf    = (ushort*)(ws + 22806528);      //  8,388,608 B [4096][1024]

    // 1) fp32 -> bf16 casts + weight packing
    convert_kernel<<<6656, 256, 0, stream>>>(x, qp, kp, vp, op, x_bf, wall_bf, op_bf);
    // 2) fused q/k/v projection: qkv[4096][1152] = x_bf @ wall^T
    gemm_mfma_bt<true><<<dim3(1152 / 128, 4096 / 128), 256, 0, stream>>>(
        x_bf, wall_bf, qkv, 4096, 1152, 1024);
    // 3) V^T for attention PV
    transpose_v_kernel<<<64, 256, 0, stream>>>(qkv, vt_bf);
    // 4) flash attention -> o_bf [4096][1024]
    attn_mfma_kernel<<<1024, 256, 0, stream>>>(qkv, vt_bf, o_bf);
    // 5) out = o_bf @ op^T (fp32 out)
    gemm_mfma_bt<false><<<dim3(1024 / 128, 4096 / 128), 256, 0, stream>>>(
        o_bf, op_bf, out, 4096, 1024, 1024);
}

// Round 4
// 218.520 us; speedup vs baseline: 7.0401x; 1.1410x over previous
//
#include <hip/hip_runtime.h>
#include <math.h>

// Problem constants: B=2, N=2048, D=1024, H=16, K=V=64
typedef __bf16  bf16x8  __attribute__((ext_vector_type(8)));
typedef float   f32x4   __attribute__((ext_vector_type(4)));
typedef ushort  u16x8   __attribute__((ext_vector_type(8)));

static __device__ __forceinline__ ushort f2bf(float f) {
    unsigned u = __float_as_uint(f);
    unsigned r = (u + 0x7fffu + ((u >> 16) & 1u)) >> 16;   // RNE
    return (ushort)r;
}
static __device__ __forceinline__ unsigned pack2bf(float a, float b) {
    return (unsigned)f2bf(a) | ((unsigned)f2bf(b) << 16);
}

// async global->LDS, 16B per lane (dest must be linear in lane index)
static __device__ __forceinline__ void gload_lds16(const ushort* g, ushort* l) {
    __builtin_amdgcn_global_load_lds(
        (const __attribute__((address_space(1))) unsigned int*)g,
        (__attribute__((address_space(3))) unsigned int*)l, 16, 0, 0);
}

// ---------------- convert: fp32 -> bf16, pack weights ----------------
// wall[1152][1024]: rows 0..1023 = query_proj (hk-major, already B^T);
//                   rows 1024..1087 = key_proj^T; rows 1088..1151 = value_proj^T
__global__ __launch_bounds__(256) void convert_kernel(
    const float* __restrict__ x, const float* __restrict__ qp,
    const float* __restrict__ kp, const float* __restrict__ vp,
    const float* __restrict__ op,
    ushort* __restrict__ x_bf, ushort* __restrict__ wall_bf,
    ushort* __restrict__ op_bf)
{
    const int bid = blockIdx.x, t = threadIdx.x;
    if (bid < 4096) {                       // x: 1M float4
        const int i = bid * 256 + t;
        const float4 v = ((const float4*)x)[i];
        ushort4 s; s.x = f2bf(v.x); s.y = f2bf(v.y); s.z = f2bf(v.z); s.w = f2bf(v.w);
        ((ushort4*)x_bf)[i] = s;
    } else if (bid < 5120) {                // qp -> wall rows 0..1023
        const int i = (bid - 4096) * 256 + t;
        const float4 v = ((const float4*)qp)[i];
        ushort4 s; s.x = f2bf(v.x); s.y = f2bf(v.y); s.z = f2bf(v.z); s.w = f2bf(v.w);
        ((ushort4*)wall_bf)[i] = s;
    } else if (bid < 6144) {                // op -> op_bf
        const int i = (bid - 5120) * 256 + t;
        const float4 v = ((const float4*)op)[i];
        ushort4 s; s.x = f2bf(v.x); s.y = f2bf(v.y); s.z = f2bf(v.z); s.w = f2bf(v.w);
        ((ushort4*)op_bf)[i] = s;
    } else if (bid < 6400) {                // kp^T -> wall rows 1024..1087
        const int i = (bid - 6144) * 256 + t;     // i = k*1024 + d
        const int k = i >> 10, d = i & 1023;
        wall_bf[(size_t)(1024 + k) * 1024 + d] = f2bf(kp[(size_t)d * 64 + k]);
    } else {                                // vp^T -> wall rows 1088..1151
        const int i = (bid - 6400) * 256 + t;
        const int v = i >> 10, d = i & 1023;
        wall_bf[(size_t)(1088 + v) * 1024 + d] = f2bf(vp[(size_t)d * 64 + v]);
    }
}

// ---------------- bf16 MFMA GEMM: C[M][N] = A[M][K] * Bt[N][K]^T ----------------
// 128x128 tile, BK=32, 4 waves (2x2), global_load_lds staging with XOR chunk swizzle.
// Columns col < scale_cols are multiplied by `scale` in the epilogue.
template <bool OUT_BF16>
__global__ __launch_bounds__(256) void gemm_mfma_bt(
    const ushort* __restrict__ A, const ushort* __restrict__ Bt,
    void* __restrict__ Cv, int M, int N, int K, int scale_cols, float scale)
{
    __shared__ alignas(16) ushort Asm[128 * 32];
    __shared__ alignas(16) ushort Bsm[128 * 32];
    const int t  = threadIdx.x;
    const int w  = t >> 6, l = t & 63;
    const int ll = l & 15, lg = l >> 4;
    const int wr = w >> 1, wc = w & 1;
    const int m0 = blockIdx.y * 128, n0 = blockIdx.x * 128;

    f32x4 acc[4][4] = {};

    for (int k0 = 0; k0 < K; k0 += 32) {
        __syncthreads();
        #pragma unroll
        for (int i = 0; i < 2; ++i) {
            const int c   = t + i * 256;
            const int row = c >> 2, p = c & 3;
            const int gp  = p ^ ((row >> 1) & 3);
            gload_lds16(&A [(size_t)(m0 + row) * K + k0 + gp * 8], &Asm[c * 8]);
            gload_lds16(&Bt[(size_t)(n0 + row) * K + k0 + gp * 8], &Bsm[c * 8]);
        }
        asm volatile("s_waitcnt vmcnt(0)" ::: "memory");
        __syncthreads();

        bf16x8 af[4], bfr[4];
        #pragma unroll
        for (int mt = 0; mt < 4; ++mt) {
            const int r = wr * 64 + mt * 16 + ll;
            af[mt] = *(const bf16x8*)&Asm[r * 32 + (lg ^ ((r >> 1) & 3)) * 8];
        }
        #pragma unroll
        for (int nt = 0; nt < 4; ++nt) {
            const int r = wc * 64 + nt * 16 + ll;
            bfr[nt] = *(const bf16x8*)&Bsm[r * 32 + (lg ^ ((r >> 1) & 3)) * 8];
        }
        #pragma unroll
        for (int mt = 0; mt < 4; ++mt)
            #pragma unroll
            for (int nt = 0; nt < 4; ++nt)
                acc[mt][nt] = __builtin_amdgcn_mfma_f32_16x16x32_bf16(af[mt], bfr[nt], acc[mt][nt], 0, 0, 0);
    }

    #pragma unroll
    for (int mt = 0; mt < 4; ++mt) {
        #pragma unroll
        for (int r = 0; r < 4; ++r) {
            const size_t row = m0 + wr * 64 + mt * 16 + lg * 4 + r;
            #pragma unroll
            for (int nt = 0; nt < 4; ++nt) {
                const int col = n0 + wc * 64 + nt * 16 + ll;
                const float f = (col < scale_cols) ? scale : 1.0f;
                const float v = acc[mt][nt][r] * f;
                if (OUT_BF16) ((ushort*)Cv)[row * N + col] = f2bf(v);
                else          ((float *)Cv)[row * N + col] = v;
            }
        }
    }
}

// ---------------- V^T build: vt[b][vd][m] from qkv cols 1088..1151 ----------------
__global__ __launch_bounds__(256) void transpose_v_kernel(
    const ushort* __restrict__ qkv, ushort* __restrict__ vt_bf)
{
    __shared__ alignas(16) ushort tl[64][72];
    const int b  = blockIdx.x >> 5;
    const int m0 = (blockIdx.x & 31) * 64;
    const int t  = threadIdx.x;
    #pragma unroll
    for (int i = 0; i < 2; ++i) {
        const int c = t + i * 256, row = c >> 3, p = c & 7;
        const uint4 v4 = *(const uint4*)&qkv[(size_t)(b * 2048 + m0 + row) * 1152 + 1088 + p * 8];
        const u16x8 v = __builtin_bit_cast(u16x8, v4);
        #pragma unroll
        for (int j = 0; j < 8; ++j) tl[p * 8 + j][row] = v[j];
    }
    __syncthreads();
    #pragma unroll
    for (int i = 0; i < 2; ++i) {
        const int c = t + i * 256, vd = c >> 3, p = c & 7;
        *(uint4*)&vt_bf[(size_t)b * 64 * 2048 + (size_t)vd * 2048 + m0 + p * 8] =
            *(const uint4*)&tl[vd][p * 8];
    }
}

// ---------------- bf16 MFMA flash attention, swapped-QK^T ----------------
// grid: B*H*(N/64) = 1024 blocks, 4 waves; wave owns 16 q-rows.
// Q pre-scaled by 0.125*log2e; softmax in exp2 domain.
// qkv [B*N][1152] (q cols 0..1023 scaled, k cols 1024..1087), vt [B][64][N].
// LDS tiles [64][64] bf16, XOR-swizzled: 16B-chunk ^= (row&7); K/V double-buffered.
__global__ __launch_bounds__(256) void attn_mfma_kernel(
    const ushort* __restrict__ qkv, const ushort* __restrict__ vt_bf,
    ushort* __restrict__ o_bf)
{
    constexpr int NN = 2048;
    __shared__ alignas(16) ushort Ks[2][64 * 64];
    __shared__ alignas(16) ushort Vs[2][64 * 64];
    __shared__ alignas(16) ushort Ps[4][16 * 64];

    const int qt = blockIdx.x & 31;
    const int h  = (blockIdx.x >> 5) & 15;
    const int b  = blockIdx.x >> 9;
    const int t  = threadIdx.x;
    const int w  = t >> 6, l = t & 63;
    const int lg = l >> 4, ll = l & 15;
    const int q0 = qt * 64 + w * 16;
    const int xr = (ll & 7) << 3;           // read-side XOR (element units)

    // Q fragments (B-operand: col = q = ll)
    bf16x8 qf[2];
    {
        const size_t base = ((size_t)(b * NN) + q0 + ll) * 1152 + h * 64;
        qf[0] = __builtin_bit_cast(bf16x8, *(const uint4*)&qkv[base + lg * 8]);
        qf[1] = __builtin_bit_cast(bf16x8, *(const uint4*)&qkv[base + 32 + lg * 8]);
    }

    f32x4 Ofrag[4] = {};
    float m_run = -1e30f, l_run = 0.f;

    // async stage of one kv-tile into buffer `buf` (pre-swizzled global source)
    auto stage = [&](int buf, int kv0) {
        #pragma unroll
        for (int i = 0; i < 2; ++i) {
            const int c = t + i * 256;            // 0..511 16B chunks
            const int row = c >> 3, ch = c & 7;
            const int gp = ch ^ (row & 7);
            gload_lds16(&qkv[((size_t)(b * NN) + kv0 + row) * 1152 + 1024 + gp * 8],
                        &Ks[buf][c * 8]);
            gload_lds16(&vt_bf[(size_t)b * 64 * NN + (size_t)row * NN + kv0 + gp * 8],
                        &Vs[buf][c * 8]);
        }
    };

    stage(0, 0);
    asm volatile("s_waitcnt vmcnt(0)" ::: "memory");
    __syncthreads();

    for (int tile = 0; tile < 32; ++tile) {
        const int cur = tile & 1;
        if (tile < 31) stage(cur ^ 1, (tile + 1) * 64);   // overlaps compute below

        const ushort* Kb = &Ks[cur][0];
        const ushort* Vb = &Vs[cur][0];

        // S^T = K . Q : lane holds S(q=ll, kv = nt*16 + lg*4 + r) in S[nt][r]
        f32x4 S[4] = {};
        #pragma unroll
        for (int ks = 0; ks < 2; ++ks) {
            bf16x8 kf[4];
            #pragma unroll
            for (int nt = 0; nt < 4; ++nt)
                kf[nt] = *(const bf16x8*)&Kb[(nt * 16 + ll) * 64 + ((ks * 32 + lg * 8) ^ xr)];
            #pragma unroll
            for (int nt = 0; nt < 4; ++nt)
                S[nt] = __builtin_amdgcn_mfma_f32_16x16x32_bf16(kf[nt], qf[ks], S[nt], 0, 0, 0);
        }

        // row max (per q): 15 in-lane fmax + 2 cross-lane
        float pm = S[0][0];
        #pragma unroll
        for (int nt = 0; nt < 4; ++nt)
            #pragma unroll
            for (int r = 0; r < 4; ++r)
                pm = fmaxf(pm, S[nt][r]);
        pm = fmaxf(pm, __shfl_xor(pm, 16));
        pm = fmaxf(pm, __shfl_xor(pm, 32));

        // defer-max: rescale only when the running max grows by > 8*log2e
        if (__any(pm > m_run + 11.5442f)) {
            const float mnew = fmaxf(m_run, pm);
            const float corr = exp2f(m_run - mnew);
            m_run = mnew;
            l_run *= corr;
            #pragma unroll
            for (int r = 0; r < 4; ++r) {
                const float cq = __shfl(corr, lg * 4 + r);
                #pragma unroll
                for (int nt = 0; nt < 4; ++nt) Ofrag[nt][r] *= cq;
            }
        }

        // P = exp2(S - m), row sum
        float psum = 0.f;
        #pragma unroll
        for (int nt = 0; nt < 4; ++nt)
            #pragma unroll
            for (int r = 0; r < 4; ++r) {
                S[nt][r] = exp2f(S[nt][r] - m_run);
                psum += S[nt][r];
            }
        psum += __shfl_xor(psum, 16);
        psum += __shfl_xor(psum, 32);
        l_run += psum;

        // pack P -> wave-private LDS [q][kv], b64 writes
        #pragma unroll
        for (int nt = 0; nt < 4; ++nt) {
            uint2 pw;
            pw.x = pack2bf(S[nt][0], S[nt][1]);
            pw.y = pack2bf(S[nt][2], S[nt][3]);
            *(uint2*)&Ps[w][ll * 64 + ((nt * 16 + lg * 4) ^ xr)] = pw;
        }

        // O += P . V
        #pragma unroll
        for (int ks = 0; ks < 2; ++ks) {
            const bf16x8 pf = *(const bf16x8*)&Ps[w][ll * 64 + ((ks * 32 + lg * 8) ^ xr)];
            bf16x8 vf[4];
            #pragma unroll
            for (int nt = 0; nt < 4; ++nt)
                vf[nt] = *(const bf16x8*)&Vb[(nt * 16 + ll) * 64 + ((ks * 32 + lg * 8) ^ xr)];
            #pragma unroll
            for (int nt = 0; nt < 4; ++nt)
                Ofrag[nt] = __builtin_amdgcn_mfma_f32_16x16x32_bf16(pf, vf[nt], Ofrag[nt], 0, 0, 0);
        }

        asm volatile("s_waitcnt vmcnt(0)" ::: "memory");   // next tile staged
        __syncthreads();
    }

    // epilogue
    const float inv = 1.0f / l_run;
    #pragma unroll
    for (int r = 0; r < 4; ++r) {
        const float iq = __shfl(inv, lg * 4 + r);
        const size_t qrow = (size_t)(b * NN) + q0 + lg * 4 + r;
        #pragma unroll
        for (int nt = 0; nt < 4; ++nt)
            o_bf[qrow * 1024 + h * 64 + nt * 16 + ll] = f2bf(Ofrag[nt][r] * iq);
    }
}

extern "C" void kernel_launch(void* const* d_in, const int* in_sizes, int n_in,
                              void* d_out, int out_size, void* d_ws, size_t ws_size,
                              hipStream_t stream)
{
    const float* x  = (const float*)d_in[0];
    const float* qp = (const float*)d_in[1];
    const float* kp = (const float*)d_in[2];
    const float* vp = (const float*)d_in[3];
    const float* op = (const float*)d_in[4];
    float* out = (float*)d_out;

    char* ws = (char*)d_ws;
    ushort* x_bf    = (ushort*)(ws);                 //  8,388,608 B
    ushort* wall_bf = (ushort*)(ws + 8388608);       //  2,359,296 B [1152][1024]
    ushort* op_bf   = (ushort*)(ws + 10747904);      //  2,097,152 B
    ushort* qkv     = (ushort*)(ws + 12845056);      //  9,437,184 B [4096][1152]
    ushort* vt_bf   = (ushort*)(ws + 22282240);      //    524,288 B [2][64][2048]
    ushort* o_bf    = (ushort*)(ws + 22806528);      //  8,388,608 B [4096][1024]

    // 1) fp32 -> bf16 casts + weight packing
    convert_kernel<<<6656, 256, 0, stream>>>(x, qp, kp, vp, op, x_bf, wall_bf, op_bf);
    // 2) fused q/k/v projection; q columns pre-scaled by 0.125*log2(e)
    gemm_mfma_bt<true><<<dim3(1152 / 128, 4096 / 128), 256, 0, stream>>>(
        x_bf, wall_bf, qkv, 4096, 1152, 1024, 1024, 0.18033688f);
    // 3) V^T for attention PV
    transpose_v_kernel<<<64, 256, 0, stream>>>(qkv, vt_bf);
    // 4) flash attention (swapped QK^T, exp2 softmax) -> o_bf
    attn_mfma_kernel<<<1024, 256, 0, stream>>>(qkv, vt_bf, o_bf);
    // 5) out = o_bf @ op^T (fp32 out)
    gemm_mfma_bt<false><<<dim3(1024 / 128, 4096 / 128), 256, 0, stream>>>(
        o_bf, op_bf, out, 4096, 1024, 1024, 0, 1.0f);
}

// Round 5
// 186.472 us; speedup vs baseline: 8.2500x; 1.1719x over previous
//
#include <hip/hip_runtime.h>
#include <math.h>

// Problem constants: B=2, N=2048, D=1024, H=16, K=V=64
typedef __bf16  bf16x8  __attribute__((ext_vector_type(8)));
typedef float   f32x4   __attribute__((ext_vector_type(4)));
typedef ushort  u16x8   __attribute__((ext_vector_type(8)));

static __device__ __forceinline__ ushort f2bf(float f) {
    unsigned u = __float_as_uint(f);
    unsigned r = (u + 0x7fffu + ((u >> 16) & 1u)) >> 16;   // RNE
    return (ushort)r;
}
// packed 2xf32 -> 2xbf16 in one instruction (low half <- a, high half <- b)
static __device__ __forceinline__ unsigned cvt_pk_bf16(float a, float b) {
    unsigned r;
    asm("v_cvt_pk_bf16_f32 %0, %1, %2" : "=v"(r) : "v"(a), "v"(b));
    return r;
}

// async global->LDS, 16B per lane (dest must be linear in lane index)
static __device__ __forceinline__ void gload_lds16(const ushort* g, ushort* l) {
    __builtin_amdgcn_global_load_lds(
        (const __attribute__((address_space(1))) unsigned int*)g,
        (__attribute__((address_space(3))) unsigned int*)l, 16, 0, 0);
}

// ---------------- convert: fp32 -> bf16, pack weights ----------------
// wall[1152][1024]: rows 0..1023 = query_proj (hk-major, already B^T);
//                   rows 1024..1087 = key_proj^T; rows 1088..1151 = value_proj^T
__global__ __launch_bounds__(256) void convert_kernel(
    const float* __restrict__ x, const float* __restrict__ qp,
    const float* __restrict__ kp, const float* __restrict__ vp,
    const float* __restrict__ op,
    ushort* __restrict__ x_bf, ushort* __restrict__ wall_bf,
    ushort* __restrict__ op_bf)
{
    const int bid = blockIdx.x, t = threadIdx.x;
    if (bid < 4096) {                       // x: 1M float4
        const int i = bid * 256 + t;
        const float4 v = ((const float4*)x)[i];
        ushort4 s; s.x = f2bf(v.x); s.y = f2bf(v.y); s.z = f2bf(v.z); s.w = f2bf(v.w);
        ((ushort4*)x_bf)[i] = s;
    } else if (bid < 5120) {                // qp -> wall rows 0..1023
        const int i = (bid - 4096) * 256 + t;
        const float4 v = ((const float4*)qp)[i];
        ushort4 s; s.x = f2bf(v.x); s.y = f2bf(v.y); s.z = f2bf(v.z); s.w = f2bf(v.w);
        ((ushort4*)wall_bf)[i] = s;
    } else if (bid < 6144) {                // op -> op_bf
        const int i = (bid - 5120) * 256 + t;
        const float4 v = ((const float4*)op)[i];
        ushort4 s; s.x = f2bf(v.x); s.y = f2bf(v.y); s.z = f2bf(v.z); s.w = f2bf(v.w);
        ((ushort4*)op_bf)[i] = s;
    } else if (bid < 6400) {                // kp^T -> wall rows 1024..1087
        const int i = (bid - 6144) * 256 + t;     // i = k*1024 + d
        const int k = i >> 10, d = i & 1023;
        wall_bf[(size_t)(1024 + k) * 1024 + d] = f2bf(kp[(size_t)d * 64 + k]);
    } else {                                // vp^T -> wall rows 1088..1151
        const int i = (bid - 6400) * 256 + t;
        const int v = i >> 10, d = i & 1023;
        wall_bf[(size_t)(1088 + v) * 1024 + d] = f2bf(vp[(size_t)d * 64 + v]);
    }
}

// ---------------- bf16 MFMA GEMM: C[M][N] = A[M][K] * Bt[N][K]^T ----------------
// 128x128 tile, BK=32, 4 waves (2x2), double-buffered LDS, counted vmcnt,
// XCD chunk swizzle. Columns col < scale_cols multiplied by `scale`.
template <bool OUT_BF16>
__global__ __launch_bounds__(256) void gemm_mfma_bt(
    const ushort* __restrict__ A, const ushort* __restrict__ Bt,
    void* __restrict__ Cv, int M, int N, int K, int scale_cols, float scale)
{
    __shared__ alignas(16) ushort Asm[2][128 * 32];
    __shared__ alignas(16) ushort Bsm[2][128 * 32];
    const int t  = threadIdx.x;
    const int w  = t >> 6, l = t & 63;
    const int ll = l & 15, lg = l >> 4;
    const int wr = w >> 1, wc = w & 1;

    // XCD chunk swizzle (bijective when nwg % 8 == 0): blocks sharing an
    // A-panel (same by) land on the same XCD's L2.
    const int nwg = gridDim.x * gridDim.y;
    int lin = blockIdx.y * gridDim.x + blockIdx.x;
    if ((nwg & 7) == 0) lin = (lin & 7) * (nwg >> 3) + (lin >> 3);
    const int bx = lin % gridDim.x, by = lin / gridDim.x;
    const int m0 = by * 128, n0 = bx * 128;

    f32x4 acc[4][4] = {};

    auto stage = [&](int buf, int k0) {
        #pragma unroll
        for (int i = 0; i < 2; ++i) {
            const int c   = t + i * 256;
            const int row = c >> 2, p = c & 3;
            const int gp  = p ^ ((row >> 1) & 3);
            gload_lds16(&A [(size_t)(m0 + row) * K + k0 + gp * 8], &Asm[buf][c * 8]);
            gload_lds16(&Bt[(size_t)(n0 + row) * K + k0 + gp * 8], &Bsm[buf][c * 8]);
        }
    };

    const int NT = K >> 5;
    stage(0, 0);
    for (int it = 0; it < NT; ++it) {
        const int cur = it & 1;
        if (it + 1 < NT) {
            stage(cur ^ 1, (it + 1) * 32);
            asm volatile("s_waitcnt vmcnt(4)" ::: "memory");  // cur's 4 loads landed
        } else {
            asm volatile("s_waitcnt vmcnt(0)" ::: "memory");
        }
        __builtin_amdgcn_s_barrier();

        bf16x8 af[4], bfr[4];
        #pragma unroll
        for (int mt = 0; mt < 4; ++mt) {
            const int r = wr * 64 + mt * 16 + ll;
            af[mt] = *(const bf16x8*)&Asm[cur][r * 32 + (lg ^ ((r >> 1) & 3)) * 8];
        }
        #pragma unroll
        for (int nt = 0; nt < 4; ++nt) {
            const int r = wc * 64 + nt * 16 + ll;
            bfr[nt] = *(const bf16x8*)&Bsm[cur][r * 32 + (lg ^ ((r >> 1) & 3)) * 8];
        }
        __builtin_amdgcn_s_setprio(1);
        #pragma unroll
        for (int mt = 0; mt < 4; ++mt)
            #pragma unroll
            for (int nt = 0; nt < 4; ++nt)
                acc[mt][nt] = __builtin_amdgcn_mfma_f32_16x16x32_bf16(af[mt], bfr[nt], acc[mt][nt], 0, 0, 0);
        __builtin_amdgcn_s_setprio(0);
        __builtin_amdgcn_s_barrier();   // reads done before next stage overwrites
    }

    #pragma unroll
    for (int mt = 0; mt < 4; ++mt) {
        #pragma unroll
        for (int r = 0; r < 4; ++r) {
            const size_t row = m0 + wr * 64 + mt * 16 + lg * 4 + r;
            #pragma unroll
            for (int nt = 0; nt < 4; ++nt) {
                const int col = n0 + wc * 64 + nt * 16 + ll;
                const float f = (col < scale_cols) ? scale : 1.0f;
                const float v = acc[mt][nt][r] * f;
                if (OUT_BF16) ((ushort*)Cv)[row * N + col] = f2bf(v);
                else          ((float *)Cv)[row * N + col] = v;
            }
        }
    }
}

// ---------------- V^T build: vt[b][vd][m] from qkv cols 1088..1151 ----------------
__global__ __launch_bounds__(256) void transpose_v_kernel(
    const ushort* __restrict__ qkv, ushort* __restrict__ vt_bf)
{
    __shared__ alignas(16) ushort tl[64][72];
    const int b  = blockIdx.x >> 5;
    const int m0 = (blockIdx.x & 31) * 64;
    const int t  = threadIdx.x;
    #pragma unroll
    for (int i = 0; i < 2; ++i) {
        const int c = t + i * 256, row = c >> 3, p = c & 7;
        const uint4 v4 = *(const uint4*)&qkv[(size_t)(b * 2048 + m0 + row) * 1152 + 1088 + p * 8];
        const u16x8 v = __builtin_bit_cast(u16x8, v4);
        #pragma unroll
        for (int j = 0; j < 8; ++j) tl[p * 8 + j][row] = v[j];
    }
    __syncthreads();
    #pragma unroll
    for (int i = 0; i < 2; ++i) {
        const int c = t + i * 256, vd = c >> 3, p = c & 7;
        *(uint4*)&vt_bf[(size_t)b * 64 * 2048 + (size_t)vd * 2048 + m0 + p * 8] =
            *(const uint4*)&tl[vd][p * 8];
    }
}

// ---------------- bf16 MFMA flash attention, swapped-QK^T ----------------
// grid: B*H*(N/64) = 1024 blocks, 4 waves; wave owns 16 q-rows.
// Q pre-scaled by 0.125*log2e; softmax in exp2 domain.
// LDS tiles [64][64] bf16, XOR-swizzled: 16B-chunk ^= (row&7); K/V double-buffered.
__global__ __launch_bounds__(256) void attn_mfma_kernel(
    const ushort* __restrict__ qkv, const ushort* __restrict__ vt_bf,
    ushort* __restrict__ o_bf)
{
    constexpr int NN = 2048;
    __shared__ alignas(16) ushort Ks[2][64 * 64];
    __shared__ alignas(16) ushort Vs[2][64 * 64];
    __shared__ alignas(16) ushort Ps[4][16 * 64];

    const int qt = blockIdx.x & 31;
    const int h  = (blockIdx.x >> 5) & 15;
    const int b  = blockIdx.x >> 9;
    const int t  = threadIdx.x;
    const int w  = t >> 6, l = t & 63;
    const int lg = l >> 4, ll = l & 15;
    const int q0 = qt * 64 + w * 16;
    const int xr = (ll & 7) << 3;           // read-side XOR (element units)

    // Q fragments (B-operand: col = q = ll)
    bf16x8 qf[2];
    {
        const size_t base = ((size_t)(b * NN) + q0 + ll) * 1152 + h * 64;
        qf[0] = __builtin_bit_cast(bf16x8, *(const uint4*)&qkv[base + lg * 8]);
        qf[1] = __builtin_bit_cast(bf16x8, *(const uint4*)&qkv[base + 32 + lg * 8]);
    }

    f32x4 Ofrag[4] = {};
    float m_run = -1e30f, l_run = 0.f;   // l_run: per-lane partial (reduced at end)

    auto stage = [&](int buf, int kv0) {
        #pragma unroll
        for (int i = 0; i < 2; ++i) {
            const int c = t + i * 256;            // 0..511 16B chunks
            const int row = c >> 3, ch = c & 7;
            const int gp = ch ^ (row & 7);
            gload_lds16(&qkv[((size_t)(b * NN) + kv0 + row) * 1152 + 1024 + gp * 8],
                        &Ks[buf][c * 8]);
            gload_lds16(&vt_bf[(size_t)b * 64 * NN + (size_t)row * NN + kv0 + gp * 8],
                        &Vs[buf][c * 8]);
        }
    };

    stage(0, 0);
    asm volatile("s_waitcnt vmcnt(0)" ::: "memory");
    __syncthreads();

    for (int tile = 0; tile < 32; ++tile) {
        const int cur = tile & 1;
        if (tile < 31) stage(cur ^ 1, (tile + 1) * 64);   // overlaps compute below

        const ushort* Kb = &Ks[cur][0];
        const ushort* Vb = &Vs[cur][0];

        // S^T = K . Q : lane holds S(q=ll, kv = nt*16 + lg*4 + r) in S[nt][r]
        f32x4 S[4] = {};
        #pragma unroll
        for (int ks = 0; ks < 2; ++ks) {
            bf16x8 kf[4];
            #pragma unroll
            for (int nt = 0; nt < 4; ++nt)
                kf[nt] = *(const bf16x8*)&Kb[(nt * 16 + ll) * 64 + ((ks * 32 + lg * 8) ^ xr)];
            __builtin_amdgcn_s_setprio(1);
            #pragma unroll
            for (int nt = 0; nt < 4; ++nt)
                S[nt] = __builtin_amdgcn_mfma_f32_16x16x32_bf16(kf[nt], qf[ks], S[nt], 0, 0, 0);
            __builtin_amdgcn_s_setprio(0);
        }

        // row max (per q): in-lane fmax tree + 2 cross-lane
        float pm = S[0][0];
        #pragma unroll
        for (int nt = 0; nt < 4; ++nt)
            #pragma unroll
            for (int r = 0; r < 4; ++r)
                pm = fmaxf(pm, S[nt][r]);
        pm = fmaxf(pm, __shfl_xor(pm, 16));
        pm = fmaxf(pm, __shfl_xor(pm, 32));

        // defer-max: rescale only when running max grows by > 8*log2(e)
        if (__any(pm > m_run + 11.5442f)) {
            const float mnew = fmaxf(m_run, pm);
            const float corr = __builtin_amdgcn_exp2f(m_run - mnew);
            m_run = mnew;
            l_run *= corr;
            #pragma unroll
            for (int r = 0; r < 4; ++r) {
                const float cq = __shfl(corr, lg * 4 + r);
                #pragma unroll
                for (int nt = 0; nt < 4; ++nt) Ofrag[nt][r] *= cq;
            }
        }

        // P = exp2(S - m), per-lane partial row sum
        #pragma unroll
        for (int nt = 0; nt < 4; ++nt)
            #pragma unroll
            for (int r = 0; r < 4; ++r) {
                S[nt][r] = __builtin_amdgcn_exp2f(S[nt][r] - m_run);
                l_run += S[nt][r];
            }

        // pack P -> wave-private LDS [q][kv]: 8x v_cvt_pk + 4x ds_write_b64
        #pragma unroll
        for (int nt = 0; nt < 4; ++nt) {
            uint2 pw;
            pw.x = cvt_pk_bf16(S[nt][0], S[nt][1]);
            pw.y = cvt_pk_bf16(S[nt][2], S[nt][3]);
            *(uint2*)&Ps[w][ll * 64 + ((nt * 16 + lg * 4) ^ xr)] = pw;
        }

        // O += P . V
        #pragma unroll
        for (int ks = 0; ks < 2; ++ks) {
            const bf16x8 pf = *(const bf16x8*)&Ps[w][ll * 64 + ((ks * 32 + lg * 8) ^ xr)];
            bf16x8 vf[4];
            #pragma unroll
            for (int nt = 0; nt < 4; ++nt)
                vf[nt] = *(const bf16x8*)&Vb[(nt * 16 + ll) * 64 + ((ks * 32 + lg * 8) ^ xr)];
            __builtin_amdgcn_s_setprio(1);
            #pragma unroll
            for (int nt = 0; nt < 4; ++nt)
                Ofrag[nt] = __builtin_amdgcn_mfma_f32_16x16x32_bf16(pf, vf[nt], Ofrag[nt], 0, 0, 0);
            __builtin_amdgcn_s_setprio(0);
        }

        asm volatile("s_waitcnt vmcnt(0)" ::: "memory");   // next tile staged
        __syncthreads();
    }

    // epilogue: finish l reduction across the 4 lanes of each q, store O
    l_run += __shfl_xor(l_run, 16);
    l_run += __shfl_xor(l_run, 32);
    const float inv = 1.0f / l_run;
    #pragma unroll
    for (int r = 0; r < 4; ++r) {
        const float iq = __shfl(inv, lg * 4 + r);
        const size_t qrow = (size_t)(b * NN) + q0 + lg * 4 + r;
        #pragma unroll
        for (int nt = 0; nt < 4; ++nt)
            o_bf[qrow * 1024 + h * 64 + nt * 16 + ll] = f2bf(Ofrag[nt][r] * iq);
    }
}

extern "C" void kernel_launch(void* const* d_in, const int* in_sizes, int n_in,
                              void* d_out, int out_size, void* d_ws, size_t ws_size,
                              hipStream_t stream)
{
    const float* x  = (const float*)d_in[0];
    const float* qp = (const float*)d_in[1];
    const float* kp = (const float*)d_in[2];
    const float* vp = (const float*)d_in[3];
    const float* op = (const float*)d_in[4];
    float* out = (float*)d_out;

    char* ws = (char*)d_ws;
    ushort* x_bf    = (ushort*)(ws);                 //  8,388,608 B
    ushort* wall_bf = (ushort*)(ws + 8388608);       //  2,359,296 B [1152][1024]
    ushort* op_bf   = (ushort*)(ws + 10747904);      //  2,097,152 B
    ushort* qkv     = (ushort*)(ws + 12845056);      //  9,437,184 B [4096][1152]
    ushort* vt_bf   = (ushort*)(ws + 22282240);      //    524,288 B [2][64][2048]
    ushort* o_bf    = (ushort*)(ws + 22806528);      //  8,388,608 B [4096][1024]

    // 1) fp32 -> bf16 casts + weight packing
    convert_kernel<<<6656, 256, 0, stream>>>(x, qp, kp, vp, op, x_bf, wall_bf, op_bf);
    // 2) fused q/k/v projection; q columns pre-scaled by 0.125*log2(e)
    gemm_mfma_bt<true><<<dim3(1152 / 128, 4096 / 128), 256, 0, stream>>>(
        x_bf, wall_bf, qkv, 4096, 1152, 1024, 1024, 0.18033688f);
    // 3) V^T for attention PV
    transpose_v_kernel<<<64, 256, 0, stream>>>(qkv, vt_bf);
    // 4) flash attention (swapped QK^T, exp2 softmax) -> o_bf
    attn_mfma_kernel<<<1024, 256, 0, stream>>>(qkv, vt_bf, o_bf);
    // 5) out = o_bf @ op^T (fp32 out)
    gemm_mfma_bt<false><<<dim3(1024 / 128, 4096 / 128), 256, 0, stream>>>(
        o_bf, op_bf, out, 4096, 1024, 1024, 0, 1.0f);
}

// Round 6
// 174.641 us; speedup vs baseline: 8.8089x; 1.0677x over previous
//
#include <hip/hip_runtime.h>
#include <math.h>

// Problem constants: B=2, N=2048, D=1024, H=16, K=V=64
typedef __bf16  bf16x8  __attribute__((ext_vector_type(8)));
typedef float   f32x4   __attribute__((ext_vector_type(4)));
typedef ushort  u16x8   __attribute__((ext_vector_type(8)));

static __device__ __forceinline__ ushort f2bf(float f) {
    unsigned u = __float_as_uint(f);
    unsigned r = (u + 0x7fffu + ((u >> 16) & 1u)) >> 16;   // RNE
    return (ushort)r;
}
// packed 2xf32 -> 2xbf16 in one instruction (low half <- a, high half <- b)
static __device__ __forceinline__ unsigned cvt_pk_bf16(float a, float b) {
    unsigned r;
    asm("v_cvt_pk_bf16_f32 %0, %1, %2" : "=v"(r) : "v"(a), "v"(b));
    return r;
}

// async global->LDS, 16B per lane (dest must be linear in lane index)
static __device__ __forceinline__ void gload_lds16(const ushort* g, ushort* l) {
    __builtin_amdgcn_global_load_lds(
        (const __attribute__((address_space(1))) unsigned int*)g,
        (__attribute__((address_space(3))) unsigned int*)l, 16, 0, 0);
}

// ---------------- convert: fp32 -> bf16, pack weights ----------------
// wall[1152][1024]: rows 0..1023 = query_proj (hk-major, already B^T);
//                   rows 1024..1087 = key_proj^T; rows 1088..1151 = value_proj^T
__global__ __launch_bounds__(256) void convert_kernel(
    const float* __restrict__ x, const float* __restrict__ qp,
    const float* __restrict__ kp, const float* __restrict__ vp,
    const float* __restrict__ op,
    ushort* __restrict__ x_bf, ushort* __restrict__ wall_bf,
    ushort* __restrict__ op_bf)
{
    const int bid = blockIdx.x, t = threadIdx.x;
    if (bid < 4096) {                       // x: 1M float4
        const int i = bid * 256 + t;
        const float4 v = ((const float4*)x)[i];
        ushort4 s; s.x = f2bf(v.x); s.y = f2bf(v.y); s.z = f2bf(v.z); s.w = f2bf(v.w);
        ((ushort4*)x_bf)[i] = s;
    } else if (bid < 5120) {                // qp -> wall rows 0..1023
        const int i = (bid - 4096) * 256 + t;
        const float4 v = ((const float4*)qp)[i];
        ushort4 s; s.x = f2bf(v.x); s.y = f2bf(v.y); s.z = f2bf(v.z); s.w = f2bf(v.w);
        ((ushort4*)wall_bf)[i] = s;
    } else if (bid < 6144) {                // op -> op_bf
        const int i = (bid - 5120) * 256 + t;
        const float4 v = ((const float4*)op)[i];
        ushort4 s; s.x = f2bf(v.x); s.y = f2bf(v.y); s.z = f2bf(v.z); s.w = f2bf(v.w);
        ((ushort4*)op_bf)[i] = s;
    } else if (bid < 6400) {                // kp^T -> wall rows 1024..1087
        const int i = (bid - 6144) * 256 + t;     // i = k*1024 + d
        const int k = i >> 10, d = i & 1023;
        wall_bf[(size_t)(1024 + k) * 1024 + d] = f2bf(kp[(size_t)d * 64 + k]);
    } else {                                // vp^T -> wall rows 1088..1151
        const int i = (bid - 6400) * 256 + t;
        const int v = i >> 10, d = i & 1023;
        wall_bf[(size_t)(1088 + v) * 1024 + d] = f2bf(vp[(size_t)d * 64 + v]);
    }
}

// ---------------- bf16 MFMA GEMM: C[M][N] = A[M][K] * Bt[N][K]^T ----------------
// 128(m) x 64(n) tile, BK=64, 4 waves (2x2, wave-tile 64x32), double-buffered
// LDS, counted vmcnt, XCD chunk swizzle. cols < scale_cols scaled by `scale`.
template <bool OUT_BF16>
__global__ __launch_bounds__(256) void gemm_mfma_bt(
    const ushort* __restrict__ A, const ushort* __restrict__ Bt,
    void* __restrict__ Cv, int M, int N, int K, int scale_cols, float scale)
{
    __shared__ alignas(16) ushort Asm[2][128 * 64];   // 32 KB
    __shared__ alignas(16) ushort Bsm[2][64 * 64];    // 16 KB
    const int t  = threadIdx.x;
    const int w  = t >> 6, l = t & 63;
    const int ll = l & 15, lg = l >> 4;
    const int wr = w >> 1, wc = w & 1;

    // XCD chunk swizzle (bijective: nwg % 8 == 0 for all our grids)
    const int nwg = gridDim.x * gridDim.y;
    int lin = blockIdx.y * gridDim.x + blockIdx.x;
    if ((nwg & 7) == 0) lin = (lin & 7) * (nwg >> 3) + (lin >> 3);
    const int bx = lin % gridDim.x, by = lin / gridDim.x;
    const int m0 = by * 128, n0 = bx * 64;

    f32x4 acc[4][2] = {};

    // stage one BK=64 tile into buffer buf: rows of 64 elems = 8 chunks of 16B,
    // chunk XOR-swizzled by (row&7) on the global source side.
    auto stage = [&](int buf, int k0) {
        #pragma unroll
        for (int i = 0; i < 4; ++i) {                  // A: 1024 chunks
            const int c = t + i * 256;
            const int row = c >> 3, ch = c & 7;
            const int gp = ch ^ (row & 7);
            gload_lds16(&A[(size_t)(m0 + row) * K + k0 + gp * 8], &Asm[buf][c * 8]);
        }
        #pragma unroll
        for (int i = 0; i < 2; ++i) {                  // B: 512 chunks
            const int c = t + i * 256;
            const int row = c >> 3, ch = c & 7;
            const int gp = ch ^ (row & 7);
            gload_lds16(&Bt[(size_t)(n0 + row) * K + k0 + gp * 8], &Bsm[buf][c * 8]);
        }
    };

    const int NT = K >> 6;      // 16
    stage(0, 0);
    for (int it = 0; it < NT; ++it) {
        const int cur = it & 1;
        if (it + 1 < NT) {
            stage(cur ^ 1, (it + 1) * 64);
            asm volatile("s_waitcnt vmcnt(6)" ::: "memory");  // cur's 6 loads landed
        } else {
            asm volatile("s_waitcnt vmcnt(0)" ::: "memory");
        }
        __builtin_amdgcn_s_barrier();

        #pragma unroll
        for (int ks = 0; ks < 2; ++ks) {
            bf16x8 af[4], bfr[2];
            #pragma unroll
            for (int mt = 0; mt < 4; ++mt) {
                const int r = wr * 64 + mt * 16 + ll;
                af[mt] = *(const bf16x8*)&Asm[cur][r * 64 + ((ks * 32 + lg * 8) ^ ((r & 7) * 8))];
            }
            #pragma unroll
            for (int nt = 0; nt < 2; ++nt) {
                const int r = wc * 32 + nt * 16 + ll;
                bfr[nt] = *(const bf16x8*)&Bsm[cur][r * 64 + ((ks * 32 + lg * 8) ^ ((r & 7) * 8))];
            }
            __builtin_amdgcn_s_setprio(1);
            #pragma unroll
            for (int mt = 0; mt < 4; ++mt)
                #pragma unroll
                for (int nt = 0; nt < 2; ++nt)
                    acc[mt][nt] = __builtin_amdgcn_mfma_f32_16x16x32_bf16(af[mt], bfr[nt], acc[mt][nt], 0, 0, 0);
            __builtin_amdgcn_s_setprio(0);
        }
        __builtin_amdgcn_s_barrier();   // reads done before next stage overwrites
    }

    #pragma unroll
    for (int mt = 0; mt < 4; ++mt) {
        #pragma unroll
        for (int r = 0; r < 4; ++r) {
            const size_t row = m0 + wr * 64 + mt * 16 + lg * 4 + r;
            #pragma unroll
            for (int nt = 0; nt < 2; ++nt) {
                const int col = n0 + wc * 32 + nt * 16 + ll;
                const float f = (col < scale_cols) ? scale : 1.0f;
                const float v = acc[mt][nt][r] * f;
                if (OUT_BF16) ((ushort*)Cv)[row * N + col] = f2bf(v);
                else          ((float *)Cv)[row * N + col] = v;
            }
        }
    }
}

// ---------------- V^T build: vt[b][vd][m] from qkv cols 1088..1151 ----------------
__global__ __launch_bounds__(256) void transpose_v_kernel(
    const ushort* __restrict__ qkv, ushort* __restrict__ vt_bf)
{
    __shared__ alignas(16) ushort tl[64][72];
    const int b  = blockIdx.x >> 5;
    const int m0 = (blockIdx.x & 31) * 64;
    const int t  = threadIdx.x;
    #pragma unroll
    for (int i = 0; i < 2; ++i) {
        const int c = t + i * 256, row = c >> 3, p = c & 7;
        const uint4 v4 = *(const uint4*)&qkv[(size_t)(b * 2048 + m0 + row) * 1152 + 1088 + p * 8];
        const u16x8 v = __builtin_bit_cast(u16x8, v4);
        #pragma unroll
        for (int j = 0; j < 8; ++j) tl[p * 8 + j][row] = v[j];
    }
    __syncthreads();
    #pragma unroll
    for (int i = 0; i < 2; ++i) {
        const int c = t + i * 256, vd = c >> 3, p = c & 7;
        *(uint4*)&vt_bf[(size_t)b * 64 * 2048 + (size_t)vd * 2048 + m0 + p * 8] =
            *(const uint4*)&tl[vd][p * 8];
    }
}

// ---------------- bf16 MFMA flash attention, both MFMAs swapped ----------------
// grid: B*H*(N/64) = 1024 blocks, 4 waves; wave owns 16 q-rows.
// Q pre-scaled by 0.125*log2e; softmax in exp2 domain.
// S^T = mfma(K,Q): lane ll holds q-row ll. O^T = mfma(V^T, P^T): lane ll holds
// q-row ll too -> corr / 1/l are pure per-lane scalars (no shuffles).
__global__ __launch_bounds__(256) void attn_mfma_kernel(
    const ushort* __restrict__ qkv, const ushort* __restrict__ vt_bf,
    ushort* __restrict__ o_bf)
{
    constexpr int NN = 2048;
    __shared__ alignas(16) ushort Ks[2][64 * 64];
    __shared__ alignas(16) ushort Vs[2][64 * 64];
    __shared__ alignas(16) ushort Ps[4][16 * 64];

    const int qt = blockIdx.x & 31;
    const int h  = (blockIdx.x >> 5) & 15;
    const int b  = blockIdx.x >> 9;
    const int t  = threadIdx.x;
    const int w  = t >> 6, l = t & 63;
    const int lg = l >> 4, ll = l & 15;
    const int q0 = qt * 64 + w * 16;
    const int xr = (ll & 7) << 3;           // read-side XOR (element units)

    // Q fragments (B-operand: col = q = ll)
    bf16x8 qf[2];
    {
        const size_t base = ((size_t)(b * NN) + q0 + ll) * 1152 + h * 64;
        qf[0] = __builtin_bit_cast(bf16x8, *(const uint4*)&qkv[base + lg * 8]);
        qf[1] = __builtin_bit_cast(bf16x8, *(const uint4*)&qkv[base + 32 + lg * 8]);
    }

    f32x4 Ofrag[4] = {};                 // O^T: lane ll = q; vd = nt*16+lg*4+r
    float m_run = -1e30f, l_run = 0.f;   // per-lane (q = ll); l partial over lg

    auto stage = [&](int buf, int kv0) {
        #pragma unroll
        for (int i = 0; i < 2; ++i) {
            const int c = t + i * 256;            // 0..511 16B chunks
            const int row = c >> 3, ch = c & 7;
            const int gp = ch ^ (row & 7);
            gload_lds16(&qkv[((size_t)(b * NN) + kv0 + row) * 1152 + 1024 + gp * 8],
                        &Ks[buf][c * 8]);
            gload_lds16(&vt_bf[(size_t)b * 64 * NN + (size_t)row * NN + kv0 + gp * 8],
                        &Vs[buf][c * 8]);
        }
    };

    stage(0, 0);
    asm volatile("s_waitcnt vmcnt(0)" ::: "memory");
    __syncthreads();

    for (int tile = 0; tile < 32; ++tile) {
        const int cur = tile & 1;
        if (tile < 31) stage(cur ^ 1, (tile + 1) * 64);   // overlaps compute below

        const ushort* Kb = &Ks[cur][0];
        const ushort* Vb = &Vs[cur][0];

        // S^T = K . Q : lane holds S(q=ll, kv = nt*16 + lg*4 + r)
        f32x4 S[4] = {};
        #pragma unroll
        for (int ks = 0; ks < 2; ++ks) {
            bf16x8 kf[4];
            #pragma unroll
            for (int nt = 0; nt < 4; ++nt)
                kf[nt] = *(const bf16x8*)&Kb[(nt * 16 + ll) * 64 + ((ks * 32 + lg * 8) ^ xr)];
            __builtin_amdgcn_s_setprio(1);
            #pragma unroll
            for (int nt = 0; nt < 4; ++nt)
                S[nt] = __builtin_amdgcn_mfma_f32_16x16x32_bf16(kf[nt], qf[ks], S[nt], 0, 0, 0);
            __builtin_amdgcn_s_setprio(0);
        }

        // row max (per q = per lane) + 2 cross-lane folds
        float pm = S[0][0];
        #pragma unroll
        for (int nt = 0; nt < 4; ++nt)
            #pragma unroll
            for (int r = 0; r < 4; ++r)
                pm = fmaxf(pm, S[nt][r]);
        pm = fmaxf(pm, __shfl_xor(pm, 16));
        pm = fmaxf(pm, __shfl_xor(pm, 32));

        // defer-max: rescale only when running max grows by > 8*log2(e)
        if (__any(pm > m_run + 11.5442f)) {
            const float mnew = fmaxf(m_run, pm);
            const float corr = __builtin_amdgcn_exp2f(m_run - mnew);
            m_run = mnew;
            l_run *= corr;
            #pragma unroll
            for (int nt = 0; nt < 4; ++nt)
                #pragma unroll
                for (int r = 0; r < 4; ++r) Ofrag[nt][r] *= corr;   // per-lane scalar
        }

        // P = exp2(S - m), per-lane partial row sum
        #pragma unroll
        for (int nt = 0; nt < 4; ++nt)
            #pragma unroll
            for (int r = 0; r < 4; ++r) {
                S[nt][r] = __builtin_amdgcn_exp2f(S[nt][r] - m_run);
                l_run += S[nt][r];
            }

        // pack P -> wave-private LDS [q][kv]: 8x v_cvt_pk + 4x ds_write_b64
        #pragma unroll
        for (int nt = 0; nt < 4; ++nt) {
            uint2 pw;
            pw.x = cvt_pk_bf16(S[nt][0], S[nt][1]);
            pw.y = cvt_pk_bf16(S[nt][2], S[nt][3]);
            *(uint2*)&Ps[w][ll * 64 + ((nt * 16 + lg * 4) ^ xr)] = pw;
        }

        // O^T += V^T . P^T  (A = V^T rows vd; B = P^T cols q — same LDS reads)
        #pragma unroll
        for (int ks = 0; ks < 2; ++ks) {
            const bf16x8 pf = *(const bf16x8*)&Ps[w][ll * 64 + ((ks * 32 + lg * 8) ^ xr)];
            bf16x8 vf[4];
            #pragma unroll
            for (int nt = 0; nt < 4; ++nt)
                vf[nt] = *(const bf16x8*)&Vb[(nt * 16 + ll) * 64 + ((ks * 32 + lg * 8) ^ xr)];
            __builtin_amdgcn_s_setprio(1);
            #pragma unroll
            for (int nt = 0; nt < 4; ++nt)
                Ofrag[nt] = __builtin_amdgcn_mfma_f32_16x16x32_bf16(vf[nt], pf, Ofrag[nt], 0, 0, 0);
            __builtin_amdgcn_s_setprio(0);
        }

        asm volatile("s_waitcnt vmcnt(0)" ::: "memory");   // next tile staged
        __syncthreads();
    }

    // epilogue: finish l reduction across the 4 lanes of each q; per-lane store
    l_run += __shfl_xor(l_run, 16);
    l_run += __shfl_xor(l_run, 32);
    const float inv = 1.0f / l_run;
    const size_t obase = ((size_t)(b * NN) + q0 + ll) * 1024 + h * 64;
    #pragma unroll
    for (int nt = 0; nt < 4; ++nt) {
        #pragma unroll
        for (int rp = 0; rp < 2; ++rp) {
            const unsigned pw = cvt_pk_bf16(Ofrag[nt][rp * 2] * inv,
                                            Ofrag[nt][rp * 2 + 1] * inv);
            *(unsigned*)&o_bf[obase + nt * 16 + lg * 4 + rp * 2] = pw;
        }
    }
}

extern "C" void kernel_launch(void* const* d_in, const int* in_sizes, int n_in,
                              void* d_out, int out_size, void* d_ws, size_t ws_size,
                              hipStream_t stream)
{
    const float* x  = (const float*)d_in[0];
    const float* qp = (const float*)d_in[1];
    const float* kp = (const float*)d_in[2];
    const float* vp = (const float*)d_in[3];
    const float* op = (const float*)d_in[4];
    float* out = (float*)d_out;

    char* ws = (char*)d_ws;
    ushort* x_bf    = (ushort*)(ws);                 //  8,388,608 B
    ushort* wall_bf = (ushort*)(ws + 8388608);       //  2,359,296 B [1152][1024]
    ushort* op_bf   = (ushort*)(ws + 10747904);      //  2,097,152 B
    ushort* qkv     = (ushort*)(ws + 12845056);      //  9,437,184 B [4096][1152]
    ushort* vt_bf   = (ushort*)(ws + 22282240);      //    524,288 B [2][64][2048]
    ushort* o_bf    = (ushort*)(ws + 22806528);      //  8,388,608 B [4096][1024]

    // 1) fp32 -> bf16 casts + weight packing
    convert_kernel<<<6656, 256, 0, stream>>>(x, qp, kp, vp, op, x_bf, wall_bf, op_bf);
    // 2) fused q/k/v projection; q columns pre-scaled by 0.125*log2(e)
    gemm_mfma_bt<true><<<dim3(1152 / 64, 4096 / 128), 256, 0, stream>>>(
        x_bf, wall_bf, qkv, 4096, 1152, 1024, 1024, 0.18033688f);
    // 3) V^T for attention PV
    transpose_v_kernel<<<64, 256, 0, stream>>>(qkv, vt_bf);
    // 4) flash attention (both-swapped MFMAs, exp2 softmax) -> o_bf
    attn_mfma_kernel<<<1024, 256, 0, stream>>>(qkv, vt_bf, o_bf);
    // 5) out = o_bf @ op^T (fp32 out)
    gemm_mfma_bt<false><<<dim3(1024 / 64, 4096 / 128), 256, 0, stream>>>(
        o_bf, op_bf, out, 4096, 1024, 1024, 0, 1.0f);
}